// Round 14
// baseline (2143.950 us; speedup 1.0000x reference)
//
#include <hip/hip_runtime.h>

#define NUM_NODES 2000
#define N_EDGES   32000
#define BT        192               // B*T = 16*12
#define NODE_F4   1536              // BT*F_IN/4 float4 per node
#define RPC       8                 // rows per chunk (1 KB/node slab)
#define NCHUNK    24                // 192 / 8
#define NPB       16                // nodes per fused block
#define NODEBLKS  (NUM_NODES / NPB) // 125
#define CHUNKS_PER_XCD 3            // 24 / 8 XCDs

// ---- CSR build (4-kernel chain — proven correct R1/R7/R13) -------------

__global__ __launch_bounds__(256) void k_zero(int* deg, int* cursor) {
    int i = blockIdx.x * 256 + threadIdx.x;
    if (i < NUM_NODES) { deg[i] = 0; cursor[i] = 0; }
}

__global__ __launch_bounds__(256) void k_count(const int* __restrict__ src, int* deg) {
    int e = blockIdx.x * 256 + threadIdx.x;
    if (e < N_EDGES) atomicAdd(&deg[src[e]], 1);
}

__global__ __launch_bounds__(256) void k_scan(const int* __restrict__ deg, int* __restrict__ offs) {
    __shared__ int part[256];
    __shared__ int pre[257];
    int t = threadIdx.x;
    int base = t * 8;
    int s = 0;
#pragma unroll
    for (int i = 0; i < 8; i++) { int idx = base + i; if (idx < NUM_NODES) s += deg[idx]; }
    part[t] = s;
    __syncthreads();
    if (t == 0) {
        int r = 0;
        for (int i = 0; i < 256; i++) { pre[i] = r; r += part[i]; }
        pre[256] = r;
    }
    __syncthreads();
    int run = pre[t];
#pragma unroll
    for (int i = 0; i < 8; i++) {
        int idx = base + i;
        if (idx < NUM_NODES) { offs[idx] = run; run += deg[idx]; }
    }
    if (t == 0) offs[NUM_NODES] = pre[256];
}

__global__ __launch_bounds__(256) void k_scatter(const int* __restrict__ src, const int* __restrict__ dst,
                                                 const int* __restrict__ offs, int* cursor,
                                                 int* __restrict__ nbr) {
    int e = blockIdx.x * 256 + threadIdx.x;
    if (e < N_EDGES) {
        int s = src[e];
        int pos = atomicAdd(&cursor[s], 1);
        nbr[offs[s] + pos] = dst[e];
    }
}

// ---- fused: out[...,0:32] = relu(x@W), out[...,32:64] = relu(mean(x[nbr])@W)
// Thread-per-row: thread owns one full 32-float bt-row. Chunk = 8 rows
// (1 KB/node slab, 2 MB per chunk -> L2-resident); XCD affinity: b&7 owns
// 3 whole chunks. Neighbor-sum in 8 float4 regs; W (LDS, broadcast reads)
// applied thread-locally; self row is an L2 hit inside the same slab.
// Writes the full 256 B output row contiguously.

__global__ __launch_bounds__(128) void k_fused(const float4* __restrict__ x4,
                                               const float4* __restrict__ w4,
                                               const int* __restrict__ offs,
                                               const int* __restrict__ nbr,
                                               float4* __restrict__ out4) {
    __shared__ float4 sW4[256];          // W row k -> float4s k*8..k*8+7
    int t = threadIdx.x;                 // 0..127
    sW4[t] = w4[t];
    sW4[t + 128] = w4[t + 128];
    __syncthreads();

    int b   = blockIdx.x;                // grid = 3000 = 8 * 375 (exact)
    int xcd = b & 7;
    int j   = b >> 3;                    // 0..374
    int cix = j / NODEBLKS;              // 0..2
    int nb  = j - cix * NODEBLKS;        // 0..124
    int chunk = xcd * CHUNKS_PER_XCD + cix;

    int nl = t >> 3;                     // 0..15 node within block
    int rl = t & 7;                      // 0..7 row within chunk
    int n  = nb * NPB + nl;
    int r  = chunk * RPC + rl;           // bt row 0..191

    int beg = offs[n];
    int end = offs[n + 1];

    float4 macc[8];
#pragma unroll
    for (int q = 0; q < 8; q++) macc[q] = make_float4(0.f, 0.f, 0.f, 0.f);
    for (int i = beg; i < end; i++) {
        int d = nbr[i];
        const float4* p = x4 + (size_t)d * NODE_F4 + r * 8;
#pragma unroll
        for (int q = 0; q < 8; q++) {
            float4 v = p[q];
            macc[q].x += v.x; macc[q].y += v.y; macc[q].z += v.z; macc[q].w += v.w;
        }
    }
    int cnt = end - beg;
    float inv = 1.0f / (float)(cnt > 1 ? cnt : 1);
#pragma unroll
    for (int q = 0; q < 8; q++) {
        macc[q].x *= inv; macc[q].y *= inv; macc[q].z *= inv; macc[q].w *= inv;
    }

    float4 xr[8];
    const float4* ps = x4 + (size_t)n * NODE_F4 + r * 8;
#pragma unroll
    for (int q = 0; q < 8; q++) xr[q] = ps[q];

    float4* orow = out4 + ((size_t)n * BT + r) * 16;
    const float* xs = (const float*)xr;    // static-indexed after unroll
    const float* ms = (const float*)macc;

#pragma unroll
    for (int c4 = 0; c4 < 8; c4++) {       // self half
        float4 a = make_float4(0.f, 0.f, 0.f, 0.f);
#pragma unroll
        for (int k = 0; k < 32; k++) {
            float4 wv = sW4[k * 8 + c4];
            float xk = xs[k];
            a.x += xk * wv.x; a.y += xk * wv.y; a.z += xk * wv.z; a.w += xk * wv.w;
        }
        orow[c4] = make_float4(fmaxf(a.x, 0.f), fmaxf(a.y, 0.f),
                               fmaxf(a.z, 0.f), fmaxf(a.w, 0.f));
    }
#pragma unroll
    for (int c4 = 0; c4 < 8; c4++) {       // aggregate half
        float4 a = make_float4(0.f, 0.f, 0.f, 0.f);
#pragma unroll
        for (int k = 0; k < 32; k++) {
            float4 wv = sW4[k * 8 + c4];
            float mk = ms[k];
            a.x += mk * wv.x; a.y += mk * wv.y; a.z += mk * wv.z; a.w += mk * wv.w;
        }
        orow[8 + c4] = make_float4(fmaxf(a.x, 0.f), fmaxf(a.y, 0.f),
                                   fmaxf(a.z, 0.f), fmaxf(a.w, 0.f));
    }
}

extern "C" void kernel_launch(void* const* d_in, const int* in_sizes, int n_in,
                              void* d_out, int out_size, void* d_ws, size_t ws_size,
                              hipStream_t stream) {
    const float* x = (const float*)d_in[0];
    const float* w = (const float*)d_in[1];
    const int* esrc = (const int*)d_in[2];
    const int* edst = (const int*)d_in[3];
    float* out = (float*)d_out;

    // workspace layout (y eliminated)
    int* deg    = (int*)d_ws;        // 2000
    int* offs   = deg + 2048;        // 2001
    int* cursor = offs + 2048;       // 2000
    int* nbr    = cursor + 2048;     // 32000

    k_zero<<<(NUM_NODES + 255) / 256, 256, 0, stream>>>(deg, cursor);
    k_count<<<(N_EDGES + 255) / 256, 256, 0, stream>>>(esrc, deg);
    k_scan<<<1, 256, 0, stream>>>(deg, offs);
    k_scatter<<<(N_EDGES + 255) / 256, 256, 0, stream>>>(esrc, edst, offs, cursor, nbr);
    k_fused<<<NCHUNK * NODEBLKS, 128, 0, stream>>>((const float4*)x, (const float4*)w,
                                                   offs, nbr, (float4*)out);
}

// Round 16
// 1971.205 us; speedup vs baseline: 1.0876x; 1.0876x over previous
//
#include <hip/hip_runtime.h>

#define NUM_NODES 2000
#define N_EDGES   32000
#define BT        192               // B*T = 16*12
#define NODE_F4   1536              // BT*F_IN/4 float4 per node
#define RPC       8                 // rows per chunk (1 KB/node slab)
#define NCHUNK    24                // 192 / 8
#define NPB       16                // nodes per fused block
#define NODEBLKS  (NUM_NODES / NPB) // 125
#define CHUNKS_PER_XCD 3            // 24 / 8 XCDs

// ---- CSR build (4-kernel chain — proven correct R1/R7/R13) -------------

__global__ __launch_bounds__(256) void k_zero(int* deg, int* cursor) {
    int i = blockIdx.x * 256 + threadIdx.x;
    if (i < NUM_NODES) { deg[i] = 0; cursor[i] = 0; }
}

__global__ __launch_bounds__(256) void k_count(const int* __restrict__ src, int* deg) {
    int e = blockIdx.x * 256 + threadIdx.x;
    if (e < N_EDGES) atomicAdd(&deg[src[e]], 1);
}

__global__ __launch_bounds__(256) void k_scan(const int* __restrict__ deg, int* __restrict__ offs) {
    __shared__ int part[256];
    __shared__ int pre[257];
    int t = threadIdx.x;
    int base = t * 8;
    int s = 0;
#pragma unroll
    for (int i = 0; i < 8; i++) { int idx = base + i; if (idx < NUM_NODES) s += deg[idx]; }
    part[t] = s;
    __syncthreads();
    if (t == 0) {
        int r = 0;
        for (int i = 0; i < 256; i++) { pre[i] = r; r += part[i]; }
        pre[256] = r;
    }
    __syncthreads();
    int run = pre[t];
#pragma unroll
    for (int i = 0; i < 8; i++) {
        int idx = base + i;
        if (idx < NUM_NODES) { offs[idx] = run; run += deg[idx]; }
    }
    if (t == 0) offs[NUM_NODES] = pre[256];
}

__global__ __launch_bounds__(256) void k_scatter(const int* __restrict__ src, const int* __restrict__ dst,
                                                 const int* __restrict__ offs, int* cursor,
                                                 int* __restrict__ nbr) {
    int e = blockIdx.x * 256 + threadIdx.x;
    if (e < N_EDGES) {
        int s = src[e];
        int pos = atomicAdd(&cursor[s], 1);
        nbr[offs[s] + pos] = dst[e];
    }
}

// ---- fused: out[...,0:32] = relu(x@W), out[...,32:64] = relu(mean(x[nbr])@W)
// Thread-per-row, named registers only (NO arrays / NO address-taking —
// R14's 256-VGPR scratch spill came from (float*)casts of register arrays).

#define ACC4(M, V) { M.x += V.x; M.y += V.y; M.z += V.z; M.w += V.w; }
#define SCL4(M, S) { M.x *= S; M.y *= S; M.z *= S; M.w *= S; }
// a += x[4q..4q+3] dot W rows (4q..4q+3), output cols 4*c4..4*c4+3
#define FMA_Q(Q, XV) { \
    float4 w0 = sW4[(Q * 4 + 0) * 8 + c4]; \
    float4 w1 = sW4[(Q * 4 + 1) * 8 + c4]; \
    float4 w2 = sW4[(Q * 4 + 2) * 8 + c4]; \
    float4 w3 = sW4[(Q * 4 + 3) * 8 + c4]; \
    a.x += XV.x * w0.x + XV.y * w1.x + XV.z * w2.x + XV.w * w3.x; \
    a.y += XV.x * w0.y + XV.y * w1.y + XV.z * w2.y + XV.w * w3.y; \
    a.z += XV.x * w0.z + XV.y * w1.z + XV.z * w2.z + XV.w * w3.z; \
    a.w += XV.x * w0.w + XV.y * w1.w + XV.z * w2.w + XV.w * w3.w; }
#define APPLY_W(V0, V1, V2, V3, V4, V5, V6, V7, OFF) \
    _Pragma("unroll") \
    for (int c4 = 0; c4 < 8; c4++) { \
        float4 a = make_float4(0.f, 0.f, 0.f, 0.f); \
        FMA_Q(0, V0) FMA_Q(1, V1) FMA_Q(2, V2) FMA_Q(3, V3) \
        FMA_Q(4, V4) FMA_Q(5, V5) FMA_Q(6, V6) FMA_Q(7, V7) \
        orow[(OFF) + c4] = make_float4(fmaxf(a.x, 0.f), fmaxf(a.y, 0.f), \
                                       fmaxf(a.z, 0.f), fmaxf(a.w, 0.f)); \
    }

__global__ __launch_bounds__(128, 4) void k_fused(const float4* __restrict__ x4,
                                                  const float4* __restrict__ w4,
                                                  const int* __restrict__ offs,
                                                  const int* __restrict__ nbr,
                                                  float4* __restrict__ out4) {
    __shared__ float4 sW4[256];          // W row k -> float4s k*8..k*8+7
    int t = threadIdx.x;                 // 0..127
    sW4[t] = w4[t];
    sW4[t + 128] = w4[t + 128];
    __syncthreads();

    int b   = blockIdx.x;                // grid = 3000 = 8 * 375 (exact)
    int xcd = b & 7;
    int j   = b >> 3;                    // 0..374
    int cix = j / NODEBLKS;              // 0..2
    int nb  = j - cix * NODEBLKS;        // 0..124
    int chunk = xcd * CHUNKS_PER_XCD + cix;

    int nl = t >> 3;                     // 0..15 node within block
    int rl = t & 7;                      // 0..7 row within chunk
    int n  = nb * NPB + nl;
    int r  = chunk * RPC + rl;           // bt row 0..191

    int beg = offs[n];
    int end = offs[n + 1];

    float4 m0 = make_float4(0.f,0.f,0.f,0.f), m1 = m0, m2 = m0, m3 = m0,
           m4 = m0, m5 = m0, m6 = m0, m7 = m0;
    for (int i = beg; i < end; i++) {
        int d = nbr[i];
        const float4* p = x4 + (size_t)d * NODE_F4 + r * 8;
        float4 v0 = p[0], v1 = p[1], v2 = p[2], v3 = p[3];
        float4 v4 = p[4], v5 = p[5], v6 = p[6], v7 = p[7];
        ACC4(m0, v0) ACC4(m1, v1) ACC4(m2, v2) ACC4(m3, v3)
        ACC4(m4, v4) ACC4(m5, v5) ACC4(m6, v6) ACC4(m7, v7)
    }
    int cnt = end - beg;
    float inv = 1.0f / (float)(cnt > 1 ? cnt : 1);
    SCL4(m0, inv) SCL4(m1, inv) SCL4(m2, inv) SCL4(m3, inv)
    SCL4(m4, inv) SCL4(m5, inv) SCL4(m6, inv) SCL4(m7, inv)

    float4* orow = out4 + ((size_t)n * BT + r) * 16;

    // aggregate half first (m* die after this, freeing registers)
    APPLY_W(m0, m1, m2, m3, m4, m5, m6, m7, 8)

    const float4* ps = x4 + (size_t)n * NODE_F4 + r * 8;
    float4 s0 = ps[0], s1 = ps[1], s2 = ps[2], s3 = ps[3];
    float4 s4 = ps[4], s5 = ps[5], s6 = ps[6], s7 = ps[7];
    APPLY_W(s0, s1, s2, s3, s4, s5, s6, s7, 0)
}

extern "C" void kernel_launch(void* const* d_in, const int* in_sizes, int n_in,
                              void* d_out, int out_size, void* d_ws, size_t ws_size,
                              hipStream_t stream) {
    const float* x = (const float*)d_in[0];
    const float* w = (const float*)d_in[1];
    const int* esrc = (const int*)d_in[2];
    const int* edst = (const int*)d_in[3];
    float* out = (float*)d_out;

    // workspace layout (y eliminated)
    int* deg    = (int*)d_ws;        // 2000
    int* offs   = deg + 2048;        // 2001
    int* cursor = offs + 2048;       // 2000
    int* nbr    = cursor + 2048;     // 32000

    k_zero<<<(NUM_NODES + 255) / 256, 256, 0, stream>>>(deg, cursor);
    k_count<<<(N_EDGES + 255) / 256, 256, 0, stream>>>(esrc, deg);
    k_scan<<<1, 256, 0, stream>>>(deg, offs);
    k_scatter<<<(N_EDGES + 255) / 256, 256, 0, stream>>>(esrc, edst, offs, cursor, nbr);
    k_fused<<<NCHUNK * NODEBLKS, 128, 0, stream>>>((const float4*)x, (const float4*)w,
                                                   offs, nbr, (float4*)out);
}